// Round 4
// baseline (1310.828 us; speedup 1.0000x reference)
//
#include <hip/hip_runtime.h>
#include <hip/hip_bf16.h>

typedef __bf16 bf16x8 __attribute__((ext_vector_type(8)));
typedef float  f32x4  __attribute__((ext_vector_type(4)));

#define NB 32
#define NS 2048
#define ND 512
#define NH 512
#define NROWS (NB*NS)
#define L2E 1.44269504f

__device__ __forceinline__ void gload16(const void* g, void* l) {
  __builtin_amdgcn_global_load_lds((const __attribute__((address_space(1))) void*)g,
                                   (__attribute__((address_space(3))) void*)l, 16, 0, 0);
}

// ---------------------------------------------------------------------------
// prep: W[d][h] (f32) -> wT[m][h][d] (bf16)
// ---------------------------------------------------------------------------
__global__ void prep_w(const float* __restrict__ Wq, const float* __restrict__ Wk,
                       const float* __restrict__ Wv, __bf16* __restrict__ wT) {
  int i = blockIdx.x * blockDim.x + threadIdx.x;
  const int total = 3 * ND * NH;
  for (; i < total; i += gridDim.x * blockDim.x) {
    int m = i / (ND * NH);
    int rem = i - m * (ND * NH);
    int h = rem >> 9;
    int d = rem & 511;
    const float* W = (m == 0) ? Wq : ((m == 1) ? Wk : Wv);
    wT[i] = (__bf16)W[(size_t)d * NH + h];
  }
}

// ---------------------------------------------------------------------------
// K1: fused 3-mode projection (unchanged from round 3).
// ---------------------------------------------------------------------------
#define K1_XOFF 0            // x: [64][1024B], seg XOR (row&7)
#define K1_WOFF 65536        // W: 2 x [512][64B], seg XOR ((h>>1)&3)
#define K1_REDM 131072       // [4][64] f32
#define K1_REDS 132096       // [4][64] f32
#define K1_LDS  133120

__global__ __launch_bounds__(512, 2)
void proj_kernel(const float* __restrict__ x, const __bf16* __restrict__ wT,
                 __bf16* __restrict__ p_out, __bf16* __restrict__ k_out,
                 float* __restrict__ L_out, __bf16* __restrict__ vt_out)
{
  __shared__ __align__(16) char smem[K1_LDS];
  char* xb = smem + K1_XOFF;
  char* wb = smem + K1_WOFF;
  float* redm = (float*)(smem + K1_REDM);
  float* reds = (float*)(smem + K1_REDS);

  const int tid = threadIdx.x;
  const int lane = tid & 63, l15 = lane & 15, g = lane >> 4;
  const int w = tid >> 6, rt = w & 1, cs = w >> 1;
  const int r0 = blockIdx.x * 64;
  const int b = r0 >> 11, s0 = r0 & (NS - 1);

  {
    int row = tid >> 3, sc = tid & 7;
    const float* xr = x + (size_t)(r0 + row) * ND;
    #pragma unroll
    for (int u = 0; u < 8; ++u) {
      int s = u * 8 + sc;
      float4 v0 = *(const float4*)(xr + s * 8);
      float4 v1 = *(const float4*)(xr + s * 8 + 4);
      bf16x8 cv;
      cv[0]=(__bf16)v0.x; cv[1]=(__bf16)v0.y; cv[2]=(__bf16)v0.z; cv[3]=(__bf16)v0.w;
      cv[4]=(__bf16)v1.x; cv[5]=(__bf16)v1.y; cv[6]=(__bf16)v1.z; cv[7]=(__bf16)v1.w;
      *(bf16x8*)(xb + row * 1024 + ((s ^ (row & 7)) * 16)) = cv;
    }
  }
  {
    #pragma unroll
    for (int u = 0; u < 4; ++u) {
      int sid = u * 512 + tid, h = sid >> 2, gg = sid & 3;
      gload16(wT + (size_t)h * ND + ((gg ^ ((h >> 1) & 3)) * 8), wb + sid * 16);
    }
  }
  __syncthreads();

  for (int m = 0; m < 3; ++m) {
    f32x4 acc[2][8];
    #pragma unroll
    for (int i2 = 0; i2 < 2; ++i2)
      #pragma unroll
      for (int ht = 0; ht < 8; ++ht) acc[i2][ht] = (f32x4){0.f,0.f,0.f,0.f};

    for (int step = 0; step < 16; ++step) {
      int gs = m * 16 + step;
      char* wcur = wb + (gs & 1) * 32768;
      if (gs + 1 < 48) {
        int gn = gs + 1, mn = gn >> 4, sn = gn & 15;
        const __bf16* wsrc = wT + (size_t)mn * (ND * NH) + sn * 32;
        char* wdst = wb + (gn & 1) * 32768;
        #pragma unroll
        for (int u = 0; u < 4; ++u) {
          int sid = u * 512 + tid, h = sid >> 2, gg = sid & 3;
          gload16(wsrc + (size_t)h * ND + ((gg ^ ((h >> 1) & 3)) * 8), wdst + sid * 16);
        }
      }
      bf16x8 a0, a1;
      {
        int ar = rt * 32 + l15;
        a0 = *(const bf16x8*)(xb + ar * 1024 + (((step * 4 + g) ^ (ar & 7)) * 16));
        ar += 16;
        a1 = *(const bf16x8*)(xb + ar * 1024 + (((step * 4 + g) ^ (ar & 7)) * 16));
      }
      #pragma unroll
      for (int ht = 0; ht < 8; ++ht) {
        int h = cs * 128 + ht * 16 + l15;
        bf16x8 bb = *(const bf16x8*)(wcur + h * 64 + ((g ^ ((h >> 1) & 3)) * 16));
        acc[0][ht] = __builtin_amdgcn_mfma_f32_16x16x32_bf16(a0, bb, acc[0][ht], 0, 0, 0);
        acc[1][ht] = __builtin_amdgcn_mfma_f32_16x16x32_bf16(a1, bb, acc[1][ht], 0, 0, 0);
      }
      __syncthreads();
    }

    if (m == 2) {
      #pragma unroll
      for (int i2 = 0; i2 < 2; ++i2) {
        int sgg = (s0 >> 3) + rt * 4 + i2 * 2 + (g >> 1);
        size_t basep = ((size_t)(b * 256 + sgg)) * 512;
        #pragma unroll
        for (int ht = 0; ht < 8; ++ht) {
          int h = cs * 128 + ht * 16 + l15;
          union { __bf16 h4[4]; ushort4 u4; } cv;
          #pragma unroll
          for (int r = 0; r < 4; ++r) cv.h4[r] = (__bf16)acc[i2][ht][r];
          *(ushort4*)(vt_out + (basep + h) * 8 + (g & 1) * 4) = cv.u4;
        }
      }
    } else {
      float mrow[2][4], tsum[2][4];
      #pragma unroll
      for (int i2 = 0; i2 < 2; ++i2)
        #pragma unroll
        for (int r = 0; r < 4; ++r) {
          float v = acc[i2][0][r];
          #pragma unroll
          for (int ht = 1; ht < 8; ++ht) v = fmaxf(v, acc[i2][ht][r]);
          v = fmaxf(v, __shfl_xor(v, 1)); v = fmaxf(v, __shfl_xor(v, 2));
          v = fmaxf(v, __shfl_xor(v, 4)); v = fmaxf(v, __shfl_xor(v, 8));
          if (l15 == 0) redm[cs * 64 + rt * 32 + i2 * 16 + g * 4 + r] = v;
        }
      __syncthreads();
      #pragma unroll
      for (int i2 = 0; i2 < 2; ++i2)
        #pragma unroll
        for (int r = 0; r < 4; ++r) {
          int row = rt * 32 + i2 * 16 + g * 4 + r;
          mrow[i2][r] = fmaxf(fmaxf(redm[row], redm[64 + row]),
                              fmaxf(redm[128 + row], redm[192 + row]));
        }
      #pragma unroll
      for (int i2 = 0; i2 < 2; ++i2)
        #pragma unroll
        for (int r = 0; r < 4; ++r) {
          float s = 0.f;
          #pragma unroll
          for (int ht = 0; ht < 8; ++ht) s += exp2f((acc[i2][ht][r] - mrow[i2][r]) * L2E);
          s += __shfl_xor(s, 1); s += __shfl_xor(s, 2);
          s += __shfl_xor(s, 4); s += __shfl_xor(s, 8);
          if (l15 == 0) reds[cs * 64 + rt * 32 + i2 * 16 + g * 4 + r] = s;
        }
      __syncthreads();
      #pragma unroll
      for (int i2 = 0; i2 < 2; ++i2)
        #pragma unroll
        for (int r = 0; r < 4; ++r) {
          int row = rt * 32 + i2 * 16 + g * 4 + r;
          tsum[i2][r] = reds[row] + reds[64 + row] + reds[128 + row] + reds[192 + row];
        }
      __bf16* dst = (m == 0) ? p_out : k_out;
      if (m == 0) {
        #pragma unroll
        for (int i2 = 0; i2 < 2; ++i2) {
          float inv[4];
          #pragma unroll
          for (int r = 0; r < 4; ++r) inv[r] = 1.f / tsum[i2][r];
          #pragma unroll
          for (int ht = 0; ht < 8; ++ht) {
            int col = cs * 128 + ht * 16 + l15;
            #pragma unroll
            for (int r = 0; r < 4; ++r) {
              int row = rt * 32 + i2 * 16 + g * 4 + r;
              dst[(size_t)(r0 + row) * NH + col] =
                  (__bf16)(exp2f((acc[i2][ht][r] - mrow[i2][r]) * L2E) * inv[r]);
            }
          }
        }
      } else {
        #pragma unroll
        for (int i2 = 0; i2 < 2; ++i2)
          #pragma unroll
          for (int ht = 0; ht < 8; ++ht) {
            int col = cs * 128 + ht * 16 + l15;
            #pragma unroll
            for (int r = 0; r < 4; ++r) {
              int row = rt * 32 + i2 * 16 + g * 4 + r;
              dst[(size_t)(r0 + row) * NH + col] = (__bf16)acc[i2][ht][r];
            }
          }
        if (cs == 0 && l15 == 0) {
          #pragma unroll
          for (int i2 = 0; i2 < 2; ++i2)
            #pragma unroll
            for (int r = 0; r < 4; ++r) {
              int row = rt * 32 + i2 * 16 + g * 4 + r;
              L_out[r0 + row] = mrow[i2][r] + __logf(tsum[i2][r]);
            }
        }
      }
      __syncthreads();
    }
  }
}

// ---------------------------------------------------------------------------
// K2: attention. BI=64, BJ=64, 32 steps, 8 waves.
// Fixes vs round 3: (a) amdgpu_waves_per_eu(2,2) -> 256-VGPR budget, Q stays
// resident (no remat/spill); (b) vf reg-loads issued BEFORE the K DMA batch
// (sched_barrier-pinned) so PV's vf wait leaves the DMA in flight.
// ---------------------------------------------------------------------------
#define KOFF 0
#define KBUFSZ 65536         // [64 j][1024B], seg XOR (j&7)
#define POFF 131072          // [64][136B]
#define PSTR 136
#define LOFF 139776          // 2048 f32
#define LREDOFF 147968       // [4][64] f32
#define A_LDS 149024

__global__ __launch_bounds__(512)
__attribute__((amdgpu_waves_per_eu(2, 2)))
void attn_kernel(const __bf16* __restrict__ p_all, const __bf16* __restrict__ k_all,
                 const float* __restrict__ L_all, const __bf16* __restrict__ vt_all,
                 float* __restrict__ out)
{
  __shared__ __align__(16) char smem[A_LDS];
  char* Pb = smem + POFF;
  float* Lld = (float*)(smem + LOFF);
  float* lred = (float*)(smem + LREDOFF);

  const int bid = blockIdx.x;
  const int b = ((bid >> 8) << 3) + (bid & 7);   // batch-grouped XCD swizzle
  const int ib = (bid >> 3) & 31;
  const int i0 = ib * 64;

  const __bf16* Pg = p_all + (size_t)b * NS * NH;
  const __bf16* Kg = k_all + (size_t)b * NS * NH;
  const float*  Lg = L_all + (size_t)b * NS;
  const __bf16* Vg = vt_all + (size_t)b * (256 * 512 * 8);
  float* Og = out + ((size_t)b * NS + i0) * NH;

  const int tid = threadIdx.x;
  const int lane = tid & 63, l15 = lane & 15, g = lane >> 4;
  const int w = tid >> 6;
  const int ibw = w >> 2, jt = w & 3;   // scores role
  const int hs = w * 64;                // PV role

  // ---- prologue: L -> LDS, Q -> regs, K(0) DMA ----
  *(float4*)(Lld + tid * 4) = *(const float4*)(Lg + tid * 4);
  bf16x8 qf[2][16];
  #pragma unroll
  for (int i2 = 0; i2 < 2; ++i2) {
    const __bf16* qrow = Pg + (size_t)(i0 + ibw * 32 + i2 * 16 + l15) * NH + g * 8;
    #pragma unroll
    for (int ks = 0; ks < 16; ++ks) qf[i2][ks] = *(const bf16x8*)(qrow + ks * 32);
  }
  #pragma unroll
  for (int u = 0; u < 8; ++u) {
    int sid = u * 512 + tid, j = sid >> 6, s6 = sid & 63;
    gload16(Kg + (size_t)j * NH + ((s6 ^ (j & 7)) * 8), smem + KOFF + sid * 16);
  }
  __syncthreads();

  f32x4 o[4][4];
  #pragma unroll
  for (int it = 0; it < 4; ++it)
    #pragma unroll
    for (int ht = 0; ht < 4; ++ht) o[it][ht] = (f32x4){0.f,0.f,0.f,0.f};
  float lsum[2][4] = {{0.f,0.f,0.f,0.f},{0.f,0.f,0.f,0.f}};

  for (int t = 0; t < NS / 64; ++t) {
    const int cur = t & 1;
    // 1. V(t) global->reg FIRST (oldest vmcnt entries -> PV wait won't drain DMA)
    bf16x8 vf[2][4];
    #pragma unroll
    for (int ks = 0; ks < 2; ++ks)
      #pragma unroll
      for (int ht = 0; ht < 4; ++ht) {
        int h = hs + ht * 16 + l15;
        int sg = t * 8 + ks * 4 + g;
        vf[ks][ht] = *(const bf16x8*)(Vg + ((size_t)sg * 512 + h) * 8);
      }
    __builtin_amdgcn_sched_barrier(0);   // pin: vf issued before DMA
    // 2. DMA K(t+1)
    if (t + 1 < NS / 64) {
      const __bf16* Ks = Kg + (size_t)(t + 1) * 64 * NH;
      char* Kd = smem + KOFF + (cur ^ 1) * KBUFSZ;
      #pragma unroll
      for (int u = 0; u < 8; ++u) {
        int sid = u * 512 + tid, j = sid >> 6, s6 = sid & 63;
        gload16(Ks + (size_t)j * NH + ((s6 ^ (j & 7)) * 8), Kd + sid * 16);
      }
    }
    // 3. scores on K(t)
    f32x4 sc0 = (f32x4){0.f,0.f,0.f,0.f}, sc1 = (f32x4){0.f,0.f,0.f,0.f};
    {
      const char* kbase = smem + KOFF + cur * KBUFSZ + (jt * 16 + l15) * 1024;
      const int jx = (jt * 16 + l15) & 7;
      #pragma unroll
      for (int ks = 0; ks < 16; ++ks) {
        bf16x8 kf = *(const bf16x8*)(kbase + (((ks * 4 + g) ^ jx) * 16));
        sc0 = __builtin_amdgcn_mfma_f32_16x16x32_bf16(qf[0][ks], kf, sc0, 0, 0, 0);
        sc1 = __builtin_amdgcn_mfma_f32_16x16x32_bf16(qf[1][ks], kf, sc1, 0, 0, 0);
      }
    }
    // 4. weights + P write (packed pairs across adjacent l15)
    {
      float LB = Lld[t * 64 + jt * 16 + l15] * L2E;
      #pragma unroll
      for (int i2 = 0; i2 < 2; ++i2) {
        f32x4 sc = i2 ? sc1 : sc0;
        #pragma unroll
        for (int r = 0; r < 4; ++r) {
          float pv = exp2f(sc[r] * L2E - LB);
          lsum[i2][r] += pv;
          float other = __shfl_xor(pv, 1);
          if ((l15 & 1) == 0) {
            union { __bf16 h; unsigned short u; } lo, hi;
            lo.h = (__bf16)pv; hi.h = (__bf16)other;
            unsigned int pk = (unsigned int)lo.u | ((unsigned int)hi.u << 16);
            int row = ibw * 32 + i2 * 16 + g * 4 + r;
            *(unsigned int*)(Pb + row * PSTR + (jt * 16 + l15) * 2) = pk;
          }
        }
      }
    }
    // B1: P visible; lgkm drain only (DMA stays in flight)
    asm volatile("s_waitcnt lgkmcnt(0)" ::: "memory");
    __builtin_amdgcn_sched_barrier(0);
    __builtin_amdgcn_s_barrier();
    __builtin_amdgcn_sched_barrier(0);
    // 5. PV: full 64 rows x own 64-h slice
    #pragma unroll
    for (int ks = 0; ks < 2; ++ks)
      #pragma unroll
      for (int it = 0; it < 4; ++it) {
        bf16x8 pa = *(const bf16x8*)(Pb + (it * 16 + l15) * PSTR + ks * 64 + g * 16);
        #pragma unroll
        for (int ht = 0; ht < 4; ++ht)
          o[it][ht] = __builtin_amdgcn_mfma_f32_16x16x32_bf16(pa, vf[ks][ht], o[it][ht], 0, 0, 0);
      }
    // B2: vmcnt(0)+barrier -> DMA complete & P reads done before reuse
    __syncthreads();
  }

  // ---- lsum reduce across l15, then across jt via LDS ----
  #pragma unroll
  for (int i2 = 0; i2 < 2; ++i2)
    #pragma unroll
    for (int r = 0; r < 4; ++r) {
      float v = lsum[i2][r];
      v += __shfl_xor(v, 1); v += __shfl_xor(v, 2);
      v += __shfl_xor(v, 4); v += __shfl_xor(v, 8);
      if (l15 == 0) lred[jt * 64 + ibw * 32 + i2 * 16 + g * 4 + r] = v;
    }
  asm volatile("s_waitcnt lgkmcnt(0)" ::: "memory");
  __syncthreads();

  #pragma unroll
  for (int it = 0; it < 4; ++it) {
    float inv[4];
    #pragma unroll
    for (int r = 0; r < 4; ++r) {
      int row = it * 16 + g * 4 + r;
      inv[r] = 1.f / (lred[row] + lred[64 + row] + lred[128 + row] + lred[192 + row]);
    }
    #pragma unroll
    for (int ht = 0; ht < 4; ++ht)
      #pragma unroll
      for (int r = 0; r < 4; ++r) {
        int row = it * 16 + g * 4 + r;
        Og[(size_t)row * NH + hs + ht * 16 + l15] = o[it][ht][r] * inv[r];
      }
  }
}

// ---------------------------------------------------------------------------
extern "C" void kernel_launch(void* const* d_in, const int* in_sizes, int n_in,
                              void* d_out, int out_size, void* d_ws, size_t ws_size,
                              hipStream_t stream) {
  const float* x  = (const float*)d_in[0];
  const float* Wq = (const float*)d_in[1];
  const float* Wk = (const float*)d_in[2];
  const float* Wv = (const float*)d_in[3];
  float* out = (float*)d_out;
  char* ws = (char*)d_ws;

  size_t off = 0;
  __bf16* wT   = (__bf16*)(ws + off); off += (size_t)3 * ND * NH * 2;   // 1.5 MB
  __bf16* p_ws = (__bf16*)(ws + off); off += (size_t)NROWS * NH * 2;    // 64 MB
  __bf16* k_ws = (__bf16*)(ws + off); off += (size_t)NROWS * NH * 2;    // 64 MB
  __bf16* vt_ws= (__bf16*)(ws + off); off += (size_t)NROWS * NH * 2;    // 64 MB (tiled)
  float*  L_ws = (float*)(ws + off);  off += (size_t)NROWS * 4;         // 0.25 MB

  prep_w<<<dim3(512), dim3(256), 0, stream>>>(Wq, Wk, Wv, wT);
  proj_kernel<<<dim3(1024), dim3(512), 0, stream>>>(x, wT, p_ws, k_ws, L_ws, vt_ws);
  attn_kernel<<<dim3(1024), dim3(512), 0, stream>>>(p_ws, k_ws, L_ws, vt_ws, out);
}

// Round 5
// 760.419 us; speedup vs baseline: 1.7238x; 1.7238x over previous
//
#include <hip/hip_runtime.h>
#include <hip/hip_bf16.h>

typedef __bf16 bf16x8 __attribute__((ext_vector_type(8)));
typedef float  f32x4  __attribute__((ext_vector_type(4)));

#define NB 32
#define NS 2048
#define ND 512
#define NH 512
#define NROWS (NB*NS)
#define L2E 1.44269504f

__device__ __forceinline__ void gload16(const void* g, void* l) {
  __builtin_amdgcn_global_load_lds((const __attribute__((address_space(1))) void*)g,
                                   (__attribute__((address_space(3))) void*)l, 16, 0, 0);
}

// ---------------------------------------------------------------------------
// prep: W[d][h] (f32) -> wT[m][h][d] (bf16)
// ---------------------------------------------------------------------------
__global__ void prep_w(const float* __restrict__ Wq, const float* __restrict__ Wk,
                       const float* __restrict__ Wv, __bf16* __restrict__ wT) {
  int i = blockIdx.x * blockDim.x + threadIdx.x;
  const int total = 3 * ND * NH;
  for (; i < total; i += gridDim.x * blockDim.x) {
    int m = i / (ND * NH);
    int rem = i - m * (ND * NH);
    int h = rem >> 9;
    int d = rem & 511;
    const float* W = (m == 0) ? Wq : ((m == 1) ? Wk : Wv);
    wT[i] = (__bf16)W[(size_t)d * NH + h];
  }
}

// ---------------------------------------------------------------------------
// K1: fused 3-mode projection (unchanged; validated).
// ---------------------------------------------------------------------------
#define K1_XOFF 0
#define K1_WOFF 65536
#define K1_REDM 131072
#define K1_REDS 132096
#define K1_LDS  133120

__global__ __launch_bounds__(512, 2)
void proj_kernel(const float* __restrict__ x, const __bf16* __restrict__ wT,
                 __bf16* __restrict__ p_out, __bf16* __restrict__ k_out,
                 float* __restrict__ L_out, __bf16* __restrict__ vt_out)
{
  __shared__ __align__(16) char smem[K1_LDS];
  char* xb = smem + K1_XOFF;
  char* wb = smem + K1_WOFF;
  float* redm = (float*)(smem + K1_REDM);
  float* reds = (float*)(smem + K1_REDS);

  const int tid = threadIdx.x;
  const int lane = tid & 63, l15 = lane & 15, g = lane >> 4;
  const int w = tid >> 6, rt = w & 1, cs = w >> 1;
  const int r0 = blockIdx.x * 64;
  const int b = r0 >> 11, s0 = r0 & (NS - 1);

  {
    int row = tid >> 3, sc = tid & 7;
    const float* xr = x + (size_t)(r0 + row) * ND;
    #pragma unroll
    for (int u = 0; u < 8; ++u) {
      int s = u * 8 + sc;
      float4 v0 = *(const float4*)(xr + s * 8);
      float4 v1 = *(const float4*)(xr + s * 8 + 4);
      bf16x8 cv;
      cv[0]=(__bf16)v0.x; cv[1]=(__bf16)v0.y; cv[2]=(__bf16)v0.z; cv[3]=(__bf16)v0.w;
      cv[4]=(__bf16)v1.x; cv[5]=(__bf16)v1.y; cv[6]=(__bf16)v1.z; cv[7]=(__bf16)v1.w;
      *(bf16x8*)(xb + row * 1024 + ((s ^ (row & 7)) * 16)) = cv;
    }
  }
  {
    #pragma unroll
    for (int u = 0; u < 4; ++u) {
      int sid = u * 512 + tid, h = sid >> 2, gg = sid & 3;
      gload16(wT + (size_t)h * ND + ((gg ^ ((h >> 1) & 3)) * 8), wb + sid * 16);
    }
  }
  __syncthreads();

  for (int m = 0; m < 3; ++m) {
    f32x4 acc[2][8];
    #pragma unroll
    for (int i2 = 0; i2 < 2; ++i2)
      #pragma unroll
      for (int ht = 0; ht < 8; ++ht) acc[i2][ht] = (f32x4){0.f,0.f,0.f,0.f};

    for (int step = 0; step < 16; ++step) {
      int gs = m * 16 + step;
      char* wcur = wb + (gs & 1) * 32768;
      if (gs + 1 < 48) {
        int gn = gs + 1, mn = gn >> 4, sn = gn & 15;
        const __bf16* wsrc = wT + (size_t)mn * (ND * NH) + sn * 32;
        char* wdst = wb + (gn & 1) * 32768;
        #pragma unroll
        for (int u = 0; u < 4; ++u) {
          int sid = u * 512 + tid, h = sid >> 2, gg = sid & 3;
          gload16(wsrc + (size_t)h * ND + ((gg ^ ((h >> 1) & 3)) * 8), wdst + sid * 16);
        }
      }
      bf16x8 a0, a1;
      {
        int ar = rt * 32 + l15;
        a0 = *(const bf16x8*)(xb + ar * 1024 + (((step * 4 + g) ^ (ar & 7)) * 16));
        ar += 16;
        a1 = *(const bf16x8*)(xb + ar * 1024 + (((step * 4 + g) ^ (ar & 7)) * 16));
      }
      #pragma unroll
      for (int ht = 0; ht < 8; ++ht) {
        int h = cs * 128 + ht * 16 + l15;
        bf16x8 bb = *(const bf16x8*)(wcur + h * 64 + ((g ^ ((h >> 1) & 3)) * 16));
        acc[0][ht] = __builtin_amdgcn_mfma_f32_16x16x32_bf16(a0, bb, acc[0][ht], 0, 0, 0);
        acc[1][ht] = __builtin_amdgcn_mfma_f32_16x16x32_bf16(a1, bb, acc[1][ht], 0, 0, 0);
      }
      __syncthreads();
    }

    if (m == 2) {
      #pragma unroll
      for (int i2 = 0; i2 < 2; ++i2) {
        int sgg = (s0 >> 3) + rt * 4 + i2 * 2 + (g >> 1);
        size_t basep = ((size_t)(b * 256 + sgg)) * 512;
        #pragma unroll
        for (int ht = 0; ht < 8; ++ht) {
          int h = cs * 128 + ht * 16 + l15;
          union { __bf16 h4[4]; ushort4 u4; } cv;
          #pragma unroll
          for (int r = 0; r < 4; ++r) cv.h4[r] = (__bf16)acc[i2][ht][r];
          *(ushort4*)(vt_out + (basep + h) * 8 + (g & 1) * 4) = cv.u4;
        }
      }
    } else {
      float mrow[2][4], tsum[2][4];
      #pragma unroll
      for (int i2 = 0; i2 < 2; ++i2)
        #pragma unroll
        for (int r = 0; r < 4; ++r) {
          float v = acc[i2][0][r];
          #pragma unroll
          for (int ht = 1; ht < 8; ++ht) v = fmaxf(v, acc[i2][ht][r]);
          v = fmaxf(v, __shfl_xor(v, 1)); v = fmaxf(v, __shfl_xor(v, 2));
          v = fmaxf(v, __shfl_xor(v, 4)); v = fmaxf(v, __shfl_xor(v, 8));
          if (l15 == 0) redm[cs * 64 + rt * 32 + i2 * 16 + g * 4 + r] = v;
        }
      __syncthreads();
      #pragma unroll
      for (int i2 = 0; i2 < 2; ++i2)
        #pragma unroll
        for (int r = 0; r < 4; ++r) {
          int row = rt * 32 + i2 * 16 + g * 4 + r;
          mrow[i2][r] = fmaxf(fmaxf(redm[row], redm[64 + row]),
                              fmaxf(redm[128 + row], redm[192 + row]));
        }
      #pragma unroll
      for (int i2 = 0; i2 < 2; ++i2)
        #pragma unroll
        for (int r = 0; r < 4; ++r) {
          float s = 0.f;
          #pragma unroll
          for (int ht = 0; ht < 8; ++ht) s += exp2f((acc[i2][ht][r] - mrow[i2][r]) * L2E);
          s += __shfl_xor(s, 1); s += __shfl_xor(s, 2);
          s += __shfl_xor(s, 4); s += __shfl_xor(s, 8);
          if (l15 == 0) reds[cs * 64 + rt * 32 + i2 * 16 + g * 4 + r] = s;
        }
      __syncthreads();
      #pragma unroll
      for (int i2 = 0; i2 < 2; ++i2)
        #pragma unroll
        for (int r = 0; r < 4; ++r) {
          int row = rt * 32 + i2 * 16 + g * 4 + r;
          tsum[i2][r] = reds[row] + reds[64 + row] + reds[128 + row] + reds[192 + row];
        }
      __bf16* dst = (m == 0) ? p_out : k_out;
      if (m == 0) {
        #pragma unroll
        for (int i2 = 0; i2 < 2; ++i2) {
          float inv[4];
          #pragma unroll
          for (int r = 0; r < 4; ++r) inv[r] = 1.f / tsum[i2][r];
          #pragma unroll
          for (int ht = 0; ht < 8; ++ht) {
            int col = cs * 128 + ht * 16 + l15;
            #pragma unroll
            for (int r = 0; r < 4; ++r) {
              int row = rt * 32 + i2 * 16 + g * 4 + r;
              dst[(size_t)(r0 + row) * NH + col] =
                  (__bf16)(exp2f((acc[i2][ht][r] - mrow[i2][r]) * L2E) * inv[r]);
            }
          }
        }
      } else {
        #pragma unroll
        for (int i2 = 0; i2 < 2; ++i2)
          #pragma unroll
          for (int ht = 0; ht < 8; ++ht) {
            int col = cs * 128 + ht * 16 + l15;
            #pragma unroll
            for (int r = 0; r < 4; ++r) {
              int row = rt * 32 + i2 * 16 + g * 4 + r;
              dst[(size_t)(r0 + row) * NH + col] = (__bf16)acc[i2][ht][r];
            }
          }
        if (cs == 0 && l15 == 0) {
          #pragma unroll
          for (int i2 = 0; i2 < 2; ++i2)
            #pragma unroll
            for (int r = 0; r < 4; ++r) {
              int row = rt * 32 + i2 * 16 + g * 4 + r;
              L_out[r0 + row] = mrow[i2][r] + __logf(tsum[i2][r]);
            }
        }
      }
      __syncthreads();
    }
  }
}

// ---------------------------------------------------------------------------
// K2: chunked GEMM attention, designed for a 128-VGPR budget (no Q in regs).
// BI=64, j-chunk 256 (8 outer), K-slice [256j][64h] ping-pong (8 kk-steps).
// Scores: 8 waves = 2 ig x 4 jg, wave tile 32i x 64j, acc 32 VGPR, operands
// from LDS (Q staged once, XOR-swizzled). P chunk (dword-XOR) aliases Kbuf0.
// PV: wave h-slice 64, V global->reg (2-deep pipeline), o = 64 VGPR.
// ---------------------------------------------------------------------------
#define QOFF 0              // [64 rows][1024B], seg-low3 XOR (row&7)
#define KOFF 65536          // 2 x [256 j][128B], seg XOR (j&7); buf0 doubles as P
#define PSTR 512            // P: [64 rows][512B], 16B-seg XOR (row&7)
#define LOFF 131072         // 2048 f32
#define LREDOFF 139264      // [4][64] f32
#define A_LDS 140288

__global__ __launch_bounds__(512, 2)
void attn_kernel(const __bf16* __restrict__ p_all, const __bf16* __restrict__ k_all,
                 const float* __restrict__ L_all, const __bf16* __restrict__ vt_all,
                 float* __restrict__ out)
{
  __shared__ __align__(16) char smem[A_LDS];
  char* Qb = smem + QOFF;
  char* Pb = smem + KOFF;            // alias K buf0
  float* Lld = (float*)(smem + LOFF);
  float* lred = (float*)(smem + LREDOFF);

  const int bid = blockIdx.x;
  const int b = ((bid >> 8) << 3) + (bid & 7);   // batch-grouped XCD swizzle
  const int ib = (bid >> 3) & 31;
  const int i0 = ib * 64;

  const __bf16* Pg = p_all + (size_t)b * NS * NH;
  const __bf16* Kg = k_all + (size_t)b * NS * NH;
  const float*  Lg = L_all + (size_t)b * NS;
  const __bf16* Vg = vt_all + (size_t)b * (256 * 512 * 8);
  float* Og = out + ((size_t)b * NS + i0) * NH;

  const int tid = threadIdx.x;
  const int lane = tid & 63, l15 = lane & 15, g = lane >> 4;
  const int w = tid >> 6;
  const int ig = w >> 2, jg = w & 3;   // scores roles
  const int hs = w * 64;               // PV role
  const int xr = l15 & 7;              // row-XOR key for LDS reads

  // ---- prologue: L -> LDS, Q -> LDS (XOR-swizzled source) ----
  *(float4*)(Lld + tid * 4) = *(const float4*)(Lg + tid * 4);
  #pragma unroll
  for (int u = 0; u < 8; ++u) {
    int sid = u * 512 + tid, row = sid >> 6, s = sid & 63;
    int sp = (s & 56) | ((s ^ row) & 7);
    gload16(Pg + (size_t)(i0 + row) * NH + sp * 8, Qb + sid * 16);
  }

  f32x4 o_[4][4];
  #pragma unroll
  for (int it = 0; it < 4; ++it)
    #pragma unroll
    for (int ht = 0; ht < 4; ++ht) o_[it][ht] = (f32x4){0.f,0.f,0.f,0.f};
  float lsum[2][4] = {{0.f,0.f,0.f,0.f},{0.f,0.f,0.f,0.f}};

  #define STAGEK(J0, KK, DST) { \
    _Pragma("unroll") \
    for (int u_ = 0; u_ < 4; ++u_) { \
      int sid_ = u_ * 512 + tid, jj_ = sid_ >> 3, ss_ = sid_ & 7; \
      gload16(Kg + (size_t)((J0) + jj_) * NH + (KK) * 64 + ((ss_ ^ (jj_ & 7)) * 8), \
              (DST) + sid_ * 16); \
    } }

  for (int outer = 0; outer < 8; ++outer) {
    const int j0 = outer * 256;
    __syncthreads();                    // S0: prev PV P-reads done (or prologue)
    STAGEK(j0, 0, smem + KOFF);
    __syncthreads();                    // S1: kk0 landed

    f32x4 acc[2][4];
    #pragma unroll
    for (int it = 0; it < 2; ++it)
      #pragma unroll
      for (int jt = 0; jt < 4; ++jt) acc[it][jt] = (f32x4){0.f,0.f,0.f,0.f};

    for (int kk = 0; kk < 8; ++kk) {
      const char* rb = smem + KOFF + (kk & 1) * 32768;
      if (kk < 7) STAGEK(j0, kk + 1, smem + KOFF + ((kk + 1) & 1) * 32768);
      #pragma unroll
      for (int sub = 0; sub < 2; ++sub) {
        bf16x8 a0, a1, bf[4];
        {
          int row = ig * 32 + l15;
          int seg = kk * 8 + ((sub * 4 + g) ^ xr);
          a0 = *(const bf16x8*)(Qb + row * 1024 + seg * 16);
          a1 = *(const bf16x8*)(Qb + (row + 16) * 1024 + seg * 16);
        }
        #pragma unroll
        for (int jt = 0; jt < 4; ++jt) {
          int j = jg * 64 + jt * 16 + l15;
          bf[jt] = *(const bf16x8*)(rb + j * 128 + (((sub * 4 + g) ^ xr) * 16));
        }
        #pragma unroll
        for (int jt = 0; jt < 4; ++jt) {
          acc[0][jt] = __builtin_amdgcn_mfma_f32_16x16x32_bf16(a0, bf[jt], acc[0][jt], 0, 0, 0);
          acc[1][jt] = __builtin_amdgcn_mfma_f32_16x16x32_bf16(a1, bf[jt], acc[1][jt], 0, 0, 0);
        }
      }
      __syncthreads();                  // S2..S9: kk+1 landed; buffers rotate
    }

    // ---- exp + pack P (dword-XOR swizzle), accumulate lsum ----
    #pragma unroll
    for (int it = 0; it < 2; ++it) {
      #pragma unroll
      for (int jt = 0; jt < 4; ++jt) {
        float LB = Lld[j0 + jg * 64 + jt * 16 + l15] * L2E;
        #pragma unroll
        for (int r = 0; r < 4; ++r) {
          float pv = exp2f(acc[it][jt][r] * L2E - LB);
          lsum[it][r] += pv;
          float other = __shfl_xor(pv, 1);
          if ((l15 & 1) == 0) {
            union { __bf16 h; unsigned short u; } lo, hi;
            lo.h = (__bf16)pv; hi.h = (__bf16)other;
            unsigned int pk = (unsigned int)lo.u | ((unsigned int)hi.u << 16);
            int row = ig * 32 + it * 16 + g * 4 + r;
            int d = jg * 32 + jt * 8 + (l15 >> 1);
            int s2 = (d >> 2) ^ (row & 7);
            *(unsigned int*)(Pb + row * PSTR + s2 * 16 + (d & 3) * 4) = pk;
          }
        }
      }
    }
    __syncthreads();                    // S10: P visible

    // ---- PV: all 64 rows x own 64-h slice; V global->reg, 2-deep pipeline ----
    #define LOADV(DST, JKS) { \
      _Pragma("unroll") \
      for (int ht_ = 0; ht_ < 4; ++ht_) { \
        int h_ = hs + ht_ * 16 + l15; \
        int sg_ = outer * 32 + (JKS) * 4 + g; \
        (DST)[ht_] = *(const bf16x8*)(Vg + ((size_t)sg_ * 512 + h_) * 8); \
      } }
    #define PVSTEP(JKS, VF) { \
      _Pragma("unroll") \
      for (int it_ = 0; it_ < 4; ++it_) { \
        int row_ = it_ * 16 + l15; \
        int sp_ = ((JKS) * 4 + g) ^ xr; \
        bf16x8 pa_ = *(const bf16x8*)(Pb + row_ * PSTR + sp_ * 16); \
        _Pragma("unroll") \
        for (int ht_ = 0; ht_ < 4; ++ht_) \
          o_[it_][ht_] = __builtin_amdgcn_mfma_f32_16x16x32_bf16(pa_, (VF)[ht_], o_[it_][ht_], 0, 0, 0); \
      } }

    {
      bf16x8 vA[4], vB[4];
      LOADV(vA, 0);
      #pragma unroll
      for (int jks = 0; jks < 8; jks += 2) {
        LOADV(vB, jks + 1);
        PVSTEP(jks, vA);
        if (jks + 2 < 8) LOADV(vA, jks + 2);
        PVSTEP(jks + 1, vB);
      }
    }
    // loop head S0 separates P reads from next outer's kk0 stage
  }

  // ---- lsum reduce (l15 lanes, then 4 jg waves via LDS) ----
  #pragma unroll
  for (int it = 0; it < 2; ++it)
    #pragma unroll
    for (int r = 0; r < 4; ++r) {
      float v = lsum[it][r];
      v += __shfl_xor(v, 1); v += __shfl_xor(v, 2);
      v += __shfl_xor(v, 4); v += __shfl_xor(v, 8);
      if (l15 == 0) lred[jg * 64 + ig * 32 + it * 16 + g * 4 + r] = v;
    }
  __syncthreads();

  #pragma unroll
  for (int it = 0; it < 4; ++it) {
    float inv[4];
    #pragma unroll
    for (int r = 0; r < 4; ++r) {
      int row = it * 16 + g * 4 + r;
      inv[r] = 1.f / (lred[row] + lred[64 + row] + lred[128 + row] + lred[192 + row]);
    }
    #pragma unroll
    for (int ht = 0; ht < 4; ++ht)
      #pragma unroll
      for (int r = 0; r < 4; ++r) {
        int row = it * 16 + g * 4 + r;
        Og[(size_t)row * NH + hs + ht * 16 + l15] = o_[it][ht][r] * inv[r];
      }
  }
}

// ---------------------------------------------------------------------------
extern "C" void kernel_launch(void* const* d_in, const int* in_sizes, int n_in,
                              void* d_out, int out_size, void* d_ws, size_t ws_size,
                              hipStream_t stream) {
  const float* x  = (const float*)d_in[0];
  const float* Wq = (const float*)d_in[1];
  const float* Wk = (const float*)d_in[2];
  const float* Wv = (const float*)d_in[3];
  float* out = (float*)d_out;
  char* ws = (char*)d_ws;

  size_t off = 0;
  __bf16* wT   = (__bf16*)(ws + off); off += (size_t)3 * ND * NH * 2;   // 1.5 MB
  __bf16* p_ws = (__bf16*)(ws + off); off += (size_t)NROWS * NH * 2;    // 64 MB
  __bf16* k_ws = (__bf16*)(ws + off); off += (size_t)NROWS * NH * 2;    // 64 MB
  __bf16* vt_ws= (__bf16*)(ws + off); off += (size_t)NROWS * NH * 2;    // 64 MB (tiled)
  float*  L_ws = (float*)(ws + off);  off += (size_t)NROWS * 4;         // 0.25 MB

  prep_w<<<dim3(512), dim3(256), 0, stream>>>(Wq, Wk, Wv, wT);
  proj_kernel<<<dim3(1024), dim3(512), 0, stream>>>(x, wT, p_ws, k_ws, L_ws, vt_ws);
  attn_kernel<<<dim3(1024), dim3(512), 0, stream>>>(p_ws, k_ws, L_ws, vt_ws, out);
}